// Round 14
// baseline (368.586 us; speedup 1.0000x reference)
//
#include <hip/hip_runtime.h>
#include <hip/hip_bf16.h>
#include <math.h>

typedef __bf16 bf16_t;
typedef __attribute__((ext_vector_type(8))) __bf16 bx8;
typedef __attribute__((ext_vector_type(4))) __bf16 bx4;
typedef __attribute__((ext_vector_type(4))) short sx4;
typedef __attribute__((ext_vector_type(4))) float fx4;

#define DEV __device__ __forceinline__

// async global->LDS, 16B per lane. LDS dest must be wave-uniform base (HW adds lane*16).
DEV void async_copy16(void* lds, const void* g) {
    __builtin_amdgcn_global_load_lds(
        (const __attribute__((address_space(1))) unsigned int*)g,
        (__attribute__((address_space(3))) unsigned int*)lds, 16, 0, 0);
}

// 16x16x16 bf16 MFMA (legacy shape, carried to gfx950; builtin name varies by ROCm)
DEV fx4 mfma16(bx4 a, bx4 b, fx4 c) {
#if __has_builtin(__builtin_amdgcn_mfma_f32_16x16x16bf16_1k)
    return __builtin_amdgcn_mfma_f32_16x16x16bf16_1k(
        __builtin_bit_cast(sx4, a), __builtin_bit_cast(sx4, b), c, 0, 0, 0);
#elif __has_builtin(__builtin_amdgcn_mfma_f32_16x16x16_bf16)
    return __builtin_amdgcn_mfma_f32_16x16x16_bf16(a, b, c, 0, 0, 0);
#else
    asm("v_mfma_f32_16x16x16_bf16 %0, %1, %2, %0" : "+v"(c) : "v"(a), "v"(b));
    return c;
#endif
}

// ---------------------------------------------------------------- fused convert (1 launch)
// segments: x 8388608 | wqkv 12582912 | wo 4194304 — all multiples of 1024, no straddle.
__global__ void __launch_bounds__(256) cvt_all(const float* __restrict__ x,
                                               const float* __restrict__ wq,
                                               const float* __restrict__ wo,
                                               bf16_t* __restrict__ xb,
                                               bf16_t* __restrict__ wqb,
                                               bf16_t* __restrict__ wob) {
    int i = (blockIdx.x * 256 + threadIdx.x) * 4;
    const float* in;
    bf16_t* out;
    int k;
    if (i < 8388608) { in = x; out = xb; k = i; }
    else if (i < 8388608 + 12582912) { in = wq; out = wqb; k = i - 8388608; }
    else { in = wo; out = wob; k = i - (8388608 + 12582912); }
    float4 v = *(const float4*)(in + k);
    bx4 o = { (__bf16)v.x, (__bf16)v.y, (__bf16)v.z, (__bf16)v.w };
    *(bx4*)(out + k) = o;
}

// ---------------------------------------------------------------- GEMM C = A[MxK] * B[NxK]^T
// r11 BK=64 m97 variant: plane-major LDS [2 kplanes][128 rows][32], 32 K-iters, 2 blk/CU.
// r12: Q columns (n0<2048) scaled by CEXP in epilogue.
// r13: V columns (n0>=4096, when VP != null) written DIRECTLY packed:
//   vp[bh][key>>2][hd][key&3] — acc rows r map to key&3 contiguously -> one bx4 store.
template <bool BF16_OUT>
__global__ void __launch_bounds__(256, 2) gemm_bt(const bf16_t* __restrict__ A,
                                                  const bf16_t* __restrict__ B,
                                                  void* __restrict__ C,
                                                  bf16_t* __restrict__ VP,
                                                  int M, int N, int K, float scale0) {
    __shared__ bf16_t As[2 * 4096];   // 16 KB: kplane*4096 + row*32 + e
    __shared__ bf16_t Bs[2 * 4096];   // 16 KB
    const int tid = threadIdx.x;
    const int w = tid >> 6, lane = tid & 63;
    const int ln = lane & 15, quad = lane >> 4;
    const int m0 = blockIdx.y * 128, n0 = blockIdx.x * 128;
    const int wm = (w >> 1) * 64, wn = (w & 1) * 64;
    const float scale = (n0 < 2048) ? scale0 : 1.0f;

    fx4 acc[4][4];
#pragma unroll
    for (int i = 0; i < 4; ++i)
#pragma unroll
        for (int j = 0; j < 4; ++j) acc[i][j] = (fx4){0.f, 0.f, 0.f, 0.f};

    for (int k0 = 0; k0 < K; k0 += 64) {
#pragma unroll
        for (int call = 0; call < 4; ++call) {
            int c = w * 256 + call * 64 + lane;
            int p = c >> 9, row = (c >> 2) & 127, piece = c & 3;
            async_copy16(As + (size_t)(w * 256 + call * 64) * 8,
                         A + (size_t)(m0 + row) * K + k0 + p * 32 + piece * 8);
            async_copy16(Bs + (size_t)(w * 256 + call * 64) * 8,
                         B + (size_t)(n0 + row) * K + k0 + p * 32 + piece * 8);
        }
        __syncthreads();

#pragma unroll
        for (int kk = 0; kk < 2; ++kk) {
            bx8 af[4], bf[4];
#pragma unroll
            for (int i = 0; i < 4; ++i)
                af[i] = *(const bx8*)(As + (size_t)kk * 4096 + (wm + i * 16 + ln) * 32 + quad * 8);
#pragma unroll
            for (int j = 0; j < 4; ++j)
                bf[j] = *(const bx8*)(Bs + (size_t)kk * 4096 + (wn + j * 16 + ln) * 32 + quad * 8);
#pragma unroll
            for (int i = 0; i < 4; ++i)
#pragma unroll
                for (int j = 0; j < 4; ++j)
                    acc[i][j] = __builtin_amdgcn_mfma_f32_16x16x32_bf16(af[i], bf[j], acc[i][j], 0, 0, 0);
        }
        __syncthreads();
    }

    if (VP != nullptr && n0 >= 4096) {
        const int h = (n0 - 4096) >> 7;
        const int bidx = m0 >> 11;
        bf16_t* vpb = VP + (size_t)(bidx * 16 + h) * 262144;
        const int key_base = (m0 & 2047) + wm;
#pragma unroll
        for (int i = 0; i < 4; ++i) {
            int key = key_base + i * 16 + quad * 4;   // multiple of 4; acc r -> key&3
#pragma unroll
            for (int j = 0; j < 4; ++j) {
                int hd = wn + j * 16 + ln;
                bx4 v = { (__bf16)acc[i][j][0], (__bf16)acc[i][j][1],
                          (__bf16)acc[i][j][2], (__bf16)acc[i][j][3] };
                *(bx4*)(vpb + (size_t)(key >> 2) * 512 + hd * 4) = v;
            }
        }
    } else {
#pragma unroll
        for (int i = 0; i < 4; ++i) {
            int mrow = m0 + wm + i * 16 + quad * 4;
#pragma unroll
            for (int j = 0; j < 4; ++j) {
                int ncol = n0 + wn + j * 16 + ln;
#pragma unroll
                for (int r = 0; r < 4; ++r) {
                    if (BF16_OUT)
                        ((bf16_t*)C)[(size_t)(mrow + r) * N + ncol] = (__bf16)(acc[i][j][r] * scale);
                    else
                        ((float*)C)[(size_t)(mrow + r) * N + ncol] = acc[i][j][r];
                }
            }
        }
    }
}

// ---------------------------------------------------------------- flash attention
// r14 re-grid for TLP: 1024 blocks (32 qt x 32 bh, XCD-remapped) = 4 blocks/CU exact;
// 64 q-rows/block (16/wave), KVBLK=64 -> LDS 32 KB (Ks 16 + Vs 16).
// r12 dual-pipe counters (Mfma 45 + VALU 44 @ 8 waves/CU) showed the per-wave schedule is
// saturated but the CU is wave-starved; 16 waves/CU fills the exp2/LDS bubbles.
// Register-only P (swapped QK^T -> S^T lane-local -> exp2 -> bx4 A-frags -> K=16 PV MFMAs).
// V from VP[bh][key/4][hd][key%4] (conflict-free ds_read_b64, linear staging).
// CEXP pre-folded into Q. Ks plane-major. no-max softmax, lsum via ones-MFMA.
__global__ void __launch_bounds__(256, 4) attn(const bf16_t* __restrict__ qkv,
                                               const bf16_t* __restrict__ vp,
                                               bf16_t* __restrict__ y) {
    __shared__ bf16_t Ks[4 * 2048];   // 16 KB: [4 pl(hd)][64 key][32 hd]
    __shared__ bf16_t Vs[8192];       // 16 KB: [16 k4][128 hd][4 k3]
    const int tid = threadIdx.x;
    const int w = tid >> 6, lane = tid & 63;
    const int ln = lane & 15, quad = lane >> 4;
    // bijective XCD remap over 1024: lin&7 carries bh low bits; all 32 qt of a bh on one XCD
    const int lin = blockIdx.x;
    const int slot = lin >> 3;
    const int bh = (lin & 7) + ((slot >> 5) << 3);
    const int qt = slot & 31;                    // 0..31, 64 q-rows each
    const int b = bh >> 4, h = bh & 15;

    const bf16_t* Qb = qkv + (size_t)(b * 2048 + qt * 64) * 6144 + h * 128;
    const bf16_t* Kb = qkv + (size_t)(b * 2048) * 6144 + 2048 + h * 128;
    const bf16_t* VPb = vp + (size_t)bh * 262144;

    // Q B-fragments: wave w owns q-rows [w*16, w*16+16)
    bx8 qf[4];
#pragma unroll
    for (int kk = 0; kk < 4; ++kk)
        qf[kk] = *(const bx8*)(Qb + (size_t)(w * 16 + ln) * 6144 + kk * 32 + quad * 8);

    const __bf16 one = (__bf16)1.0f;
    const bx4 ones4 = { one, one, one, one };

    fx4 o[8];
#pragma unroll
    for (int j = 0; j < 8; ++j) o[j] = (fx4){0.f, 0.f, 0.f, 0.f};
    fx4 lsum = (fx4){0.f, 0.f, 0.f, 0.f};

    for (int kt = 0; kt < 32; ++kt) {
        // stage 64-key tile: wave w fills K-plane w (4 KB) + V key-groups [w*4, w*4+4) (4 KB)
#pragma unroll
        for (int call = 0; call < 4; ++call) {
            int cp = call * 64 + lane;
            int row = cp >> 2, piece = cp & 3;
            async_copy16(Ks + (size_t)w * 2048 + call * 512,
                         Kb + (size_t)(kt * 64 + row) * 6144 + w * 32 + piece * 8);
            async_copy16(Vs + (size_t)w * 2048 + call * 512,
                         VPb + (size_t)kt * 8192 + (w * 4 + call) * 512 + lane * 8);
        }
        __syncthreads();

        // 2 quarters of 32 keys (= key-tiles 2q, 2q+1)
#pragma unroll
        for (int q = 0; q < 2; ++q) {
            // swapped QK^T: S^T[key=quad*4+r][q=ln]
            fx4 st[2];
            st[0] = (fx4){0.f, 0.f, 0.f, 0.f};
            st[1] = (fx4){0.f, 0.f, 0.f, 0.f};
#pragma unroll
            for (int kk = 0; kk < 4; ++kk) {
                bx8 kf0 = *(const bx8*)(Ks + (size_t)kk * 2048 + ((2 * q) * 16 + ln) * 32 + quad * 8);
                bx8 kf1 = *(const bx8*)(Ks + (size_t)kk * 2048 + ((2 * q + 1) * 16 + ln) * 32 + quad * 8);
                st[0] = __builtin_amdgcn_mfma_f32_16x16x32_bf16(kf0, qf[kk], st[0], 0, 0, 0);
                st[1] = __builtin_amdgcn_mfma_f32_16x16x32_bf16(kf1, qf[kk], st[1], 0, 0, 0);
            }

            // exp2 in-register (Q pre-scaled) -> P A-fragments for K=16 MFMA
            bx4 pa[2];
#pragma unroll
            for (int jj = 0; jj < 2; ++jj) {
                bx4 t = { (__bf16)exp2f(st[jj][0]), (__bf16)exp2f(st[jj][1]),
                          (__bf16)exp2f(st[jj][2]), (__bf16)exp2f(st[jj][3]) };
                pa[jj] = t;
            }

            // PV (K=16): o += P V over this quarter's 32 keys; lsum += P 1
#pragma unroll
            for (int jj = 0; jj < 2; ++jj) {
                const int kt8 = 2 * q + jj;
                bx4 vf[8];
#pragma unroll
                for (int j = 0; j < 8; ++j)
                    vf[j] = *(const bx4*)(Vs + (size_t)(kt8 * 4 + quad) * 512 + (j * 16 + ln) * 4);
#pragma unroll
                for (int j = 0; j < 8; ++j)
                    o[j] = mfma16(pa[jj], vf[j], o[j]);
                lsum = mfma16(pa[jj], ones4, lsum);
            }
        }
        __syncthreads();
    }

    // epilogue: y[b,t,h*128+hd] bf16 (o rows q=quad*4+r, cols d=ln)
#pragma unroll
    for (int r = 0; r < 4; ++r) {
        float rl = 1.0f / lsum[r];
#pragma unroll
        for (int j = 0; j < 8; ++j) {
            int t = qt * 64 + w * 16 + quad * 4 + r;
            int col = h * 128 + j * 16 + ln;
            y[(size_t)(b * 2048 + t) * 2048 + col] = (__bf16)(o[j][r] * rl);
        }
    }
}

// ---------------------------------------------------------------- launch
extern "C" void kernel_launch(void* const* d_in, const int* in_sizes, int n_in,
                              void* d_out, int out_size, void* d_ws, size_t ws_size,
                              hipStream_t stream) {
    const float* x    = (const float*)d_in[0];
    const float* wqkv = (const float*)d_in[1];
    const float* wo   = (const float*)d_in[2];
    float* out = (float*)d_out;
    char* ws = (char*)d_ws;
    const float CEXP = 0.08838834764831845f * 1.44269504088896340f;  // (1/sqrt(128))*log2(e)

    // workspace layout (112 MB total)
    bf16_t* Xb  = (bf16_t*)(ws);                          // 16 MB  (reused as Y after QKV GEMM)
    bf16_t* Wqb = (bf16_t*)(ws + (size_t)(16u << 20));    // 24 MB
    bf16_t* Wob = (bf16_t*)(ws + (size_t)(40u << 20));    //  8 MB
    bf16_t* QKV = (bf16_t*)(ws + (size_t)(48u << 20));    // 48 MB (V region unused)
    bf16_t* VP  = (bf16_t*)(ws + (size_t)(96u << 20));    // 16 MB
    bf16_t* Y   = Xb;

    // one fused convert launch (25165824 elems, 4/thread)
    cvt_all<<<24576, 256, 0, stream>>>(x, wqkv, wo, Xb, Wqb, Wob);

    // QKV = X * Wqkv^T [4096 x 6144]; Q cols pre-scaled by CEXP; V cols -> VP packed
    gemm_bt<true><<<dim3(48, 32), 256, 0, stream>>>(Xb, Wqb, QKV, VP, 4096, 6144, 2048, CEXP);
    // flash attention -> Y [4096 x 2048] bf16  (1024 blocks = 4/CU exact, XCD-remapped)
    attn<<<dim3(1024), 256, 0, stream>>>(QKV, VP, Y);
    // out = Y * Wo^T  [4096 x 2048] fp32
    gemm_bt<false><<<dim3(16, 32), 256, 0, stream>>>(Y, Wob, out, nullptr, 4096, 2048, 2048, 1.0f);
}